// Round 3
// baseline (50.774 us; speedup 1.0000x reference)
//
#include <hip/hip_runtime.h>
#include <hip/hip_bf16.h>

#define B_DIM 128
#define C_DIM 128
#define T_DIM 777
#define P_DIM 500
#define P_PAD 512
#define NCLS  5
#define EPSV  1e-4f
#define NT    25          // ceil(777/32)

typedef unsigned short u16;
typedef unsigned int   u32;
typedef __attribute__((ext_vector_type(8))) short short8;   // 8 bf16 = 4 VGPR
typedef __attribute__((ext_vector_type(4))) float f32x4;
typedef float float4u __attribute__((ext_vector_type(4), aligned(4)));  // stride 777 is odd -> 4B align

__device__ __forceinline__ u32 cvt_pk_bf16(float a, float b) {
    // D[15:0]=bf16(a), D[31:16]=bf16(b); HW RNE (gfx950)
    u32 r;
    asm("v_cvt_pk_bf16_f32 %0, %1, %2" : "=v"(r) : "v"(a), "v"(b));
    return r;
}

// ---------------- fused: x fp32 -> bf16 LDS (dbuf) -> MFMA -> min over t ----------------
// grid 768 = b(128) x pt(2) x th(3); block 256 (4 waves); wave owns 64 protos.
// wsmin[th][b][p] = min over the th t-range of (x2[t] - 2*x.p)   (p2/clamp/log deferred)
__global__ __launch_bounds__(256, 3) void fused_gemm_min(
    const float* __restrict__ x,
    const float* __restrict__ proto,
    float* __restrict__ wsmin) {

    const int o   = blockIdx.x;               // XCD-bijective: 768 = 8 XCD x 96
    const int xcd = o & 7, j = o >> 3;        // j: 0..95
    const int bl  = j / 6;                    // 0..15
    const int r6  = j - bl * 6;               // 0..5
    const int b   = xcd * 16 + bl;
    const int pt  = r6 & 1;
    const int th  = r6 >> 1;                  // 0..2
    const int it0 = (th == 0) ? 0 : (th == 1 ? 9 : 17);
    const int itN = (th == 0) ? 9 : (th == 1 ? 17 : NT);

    const int tid = threadIdx.x;
    const int w = tid >> 6, l = tid & 63;
    const int row16 = l & 15, kq = l >> 4;    // kq: 0..3
    const int wp = pt * 256 + w * 64;         // wave's proto base (64 rows)

    // loader: thread owns 4 c-rows x 4 t-cols (block covers 128c x 32t)
    const int c0  = (tid >> 3) << 2;          // 0..124
    const int tl0 = (tid & 7) << 2;           // 0..28

    __shared__ __align__(16) char  smem[2][32 * 256];  // dbuf: 32 t-rows x 128 c bf16, 16B-granule XOR swizzle
    __shared__ __align__(16) float x2p[2][4][32];      // dbuf per-wave x2 partials

    const float* xb = x + (size_t)b * C_DIM * T_DIM;

    // ---- prologue: prototype A-frags in registers (bf16 via cvt_pk) ----
    short8 afr[4][4];
#pragma unroll
    for (int ps = 0; ps < 4; ++ps) {
        const int r = wp + ps * 16 + row16;
#pragma unroll
        for (int kst = 0; kst < 4; ++kst) {
            const int k0 = kst * 32 + kq * 8;
            union { short8 s; u32 d[4]; } t;
            if (r < P_DIM) {
                float4 u0 = *(const float4*)(proto + r * C_DIM + k0);
                float4 u1 = *(const float4*)(proto + r * C_DIM + k0 + 4);
                t.d[0] = cvt_pk_bf16(u0.x, u0.y);
                t.d[1] = cvt_pk_bf16(u0.z, u0.w);
                t.d[2] = cvt_pk_bf16(u1.x, u1.y);
                t.d[3] = cvt_pk_bf16(u1.z, u1.w);
            } else {
                t.d[0] = t.d[1] = t.d[2] = t.d[3] = 0u;
            }
            afr[ps][kst] = t.s;
        }
    }

    float vb[4][4];   // [c-row][t-col], compile-time indexed (rule #20)
    auto loadv = [&](int it) {
        const int tb = it * 32 + tl0;
        if (tb + 3 < T_DIM) {
#pragma unroll
            for (int r = 0; r < 4; ++r) {
                float4u u = *(const float4u*)(xb + (c0 + r) * T_DIM + tb);
                vb[r][0]=u[0]; vb[r][1]=u[1]; vb[r][2]=u[2]; vb[r][3]=u[3];
            }
        } else {
#pragma unroll
            for (int r = 0; r < 4; ++r)
#pragma unroll
                for (int jj = 0; jj < 4; ++jj) {
                    const int t = tb + jj;
                    vb[r][jj] = (t < T_DIM) ? xb[(c0 + r) * T_DIM + t] : 0.f;
                }
        }
    };

    // convert vb -> bf16, write transposed+swizzled into smem[bsel]; x2 partials -> x2p[bsel]
    auto write_tile = [&](int it, int bsel) {
        const int t0 = it * 32;
        float s[4];
#pragma unroll
        for (int jj = 0; jj < 4; ++jj)
            s[jj] = vb[0][jj]*vb[0][jj] + vb[1][jj]*vb[1][jj]
                  + vb[2][jj]*vb[2][jj] + vb[3][jj]*vb[3][jj];
#pragma unroll
        for (int jj = 0; jj < 4; ++jj) {
            const u32 lo = cvt_pk_bf16(vb[0][jj], vb[1][jj]);
            const u32 hi = cvt_pk_bf16(vb[2][jj], vb[3][jj]);
            const int tl  = tl0 + jj;
            const int off = tl * 256 + (((c0 >> 3) ^ (tl & 7)) << 4) + ((c0 & 4) << 1);
            *(uint2*)(smem[bsel] + off) = make_uint2(lo, hi);
        }
#pragma unroll
        for (int m = 8; m <= 32; m <<= 1)
#pragma unroll
            for (int jj = 0; jj < 4; ++jj) s[jj] += __shfl_xor(s[jj], m);
        if ((l >> 3) == 0) {                       // lanes 0..7: tl0 == l*4
            float4 o4;
            o4.x = (t0 + tl0 + 0 < T_DIM) ? s[0] : 1e30f;   // padded t never wins the min
            o4.y = (t0 + tl0 + 1 < T_DIM) ? s[1] : 1e30f;
            o4.z = (t0 + tl0 + 2 < T_DIM) ? s[2] : 1e30f;
            o4.w = (t0 + tl0 + 3 < T_DIM) ? s[3] : 1e30f;
            *(float4*)(&x2p[bsel][w][tl0]) = o4;
        }
    };

    f32x4 minv[4];
#pragma unroll
    for (int ps = 0; ps < 4; ++ps) minv[ps] = (f32x4){1e30f, 1e30f, 1e30f, 1e30f};

    // ---- pipeline prologue ----
    loadv(it0);
    write_tile(it0, 0);
    __syncthreads();

    int cur = 0;
    for (int it = it0; it < itN; ++it) {
        const bool more = (it + 1 < itN);
        if (more) loadv(it + 1);               // issue VMEM early; latency hides under MFMA

        // ---- compute phase on smem[cur] ----
        f32x4 acc[4][2];
#pragma unroll
        for (int ps = 0; ps < 4; ++ps)
#pragma unroll
            for (int ts = 0; ts < 2; ++ts) acc[ps][ts] = (f32x4){0.f, 0.f, 0.f, 0.f};

        const char* sbase = smem[cur];
        __builtin_amdgcn_s_setprio(1);
#pragma unroll
        for (int kst = 0; kst < 4; ++kst) {
            short8 bfr[2];
#pragma unroll
            for (int ts = 0; ts < 2; ++ts) {
                const int tl = ts * 16 + row16;
                const int gr = (kst * 4 + kq) ^ (tl & 7);
                bfr[ts] = *(const short8*)(sbase + tl * 256 + (gr << 4));
            }
#pragma unroll
            for (int ps = 0; ps < 4; ++ps)
#pragma unroll
                for (int ts = 0; ts < 2; ++ts)
                    acc[ps][ts] = __builtin_amdgcn_mfma_f32_16x16x32_bf16(
                        afr[ps][kst], bfr[ts], acc[ps][ts], 0, 0, 0);
        }
        __builtin_amdgcn_s_setprio(0);

        const float x2v0 = x2p[cur][0][row16]      + x2p[cur][1][row16]
                         + x2p[cur][2][row16]      + x2p[cur][3][row16];
        const float x2v1 = x2p[cur][0][16 + row16] + x2p[cur][1][16 + row16]
                         + x2p[cur][2][16 + row16] + x2p[cur][3][16 + row16];
#pragma unroll
        for (int ps = 0; ps < 4; ++ps)
#pragma unroll
            for (int q = 0; q < 4; ++q) {
                minv[ps][q] = fminf(minv[ps][q], fmaf(-2.f, acc[ps][0][q], x2v0));
                minv[ps][q] = fminf(minv[ps][q], fmaf(-2.f, acc[ps][1][q], x2v1));
            }

        // ---- write phase for it+1 into the other buffer ----
        if (more) write_tile(it + 1, cur ^ 1);
        __syncthreads();
        cur ^= 1;
    }

    // min across the 16 t-columns (lane bits 0..3)
#pragma unroll
    for (int m = 1; m <= 8; m <<= 1)
#pragma unroll
        for (int ps = 0; ps < 4; ++ps)
#pragma unroll
            for (int q = 0; q < 4; ++q)
                minv[ps][q] = fminf(minv[ps][q], __shfl_xor(minv[ps][q], m));

    if (row16 == 0) {
#pragma unroll
        for (int ps = 0; ps < 4; ++ps) {
            const int p = wp + ps * 16 + kq * 4;   // C/D: row = kq*4+q -> p offset; q contiguous
            *(float4*)(&wsmin[((size_t)th * B_DIM + b) * P_PAD + p]) =
                make_float4(minv[ps][0], minv[ps][1], minv[ps][2], minv[ps][3]);
        }
    }
}

// ---------------- combine: p2 + 3-way min-merge + clamp + log-sim + @W ----------------
__global__ __launch_bounds__(256) void combine_logits(
    const float* __restrict__ proto, const float* __restrict__ lw,
    const float* __restrict__ wsmin, float* __restrict__ out) {
    const int b = blockIdx.x, tid = threadIdx.x;
    float a[NCLS] = {0.f, 0.f, 0.f, 0.f, 0.f};
    for (int p = tid; p < P_DIM; p += 256) {
        const float4* pr = (const float4*)(proto + p * C_DIM);
        float p2 = 0.f;
#pragma unroll
        for (int i = 0; i < 32; ++i) {
            float4 u = pr[i];
            p2 += u.x*u.x + u.y*u.y + u.z*u.z + u.w*u.w;
        }
        const float m0 = wsmin[(0 * B_DIM + b) * P_PAD + p];
        const float m1 = wsmin[(1 * B_DIM + b) * P_PAD + p];
        const float m2 = wsmin[(2 * B_DIM + b) * P_PAD + p];
        const float m  = fminf(fminf(m0, m1), m2);       // v_min3
        const float md = fmaxf(m + p2, 0.f);
        const float sim = logf((md + 1.f) / (md + EPSV));
#pragma unroll
        for (int n = 0; n < NCLS; ++n) a[n] = fmaf(sim, lw[p * NCLS + n], a[n]);
    }
#pragma unroll
    for (int m = 1; m <= 32; m <<= 1)
#pragma unroll
        for (int n = 0; n < NCLS; ++n) a[n] += __shfl_xor(a[n], m);
    __shared__ float red[4][NCLS];
    const int w = tid >> 6, l = tid & 63;
    if (l == 0) {
#pragma unroll
        for (int n = 0; n < NCLS; ++n) red[w][n] = a[n];
    }
    __syncthreads();
    if (tid < NCLS)
        out[b * NCLS + tid] = red[0][tid] + red[1][tid] + red[2][tid] + red[3][tid];
}

// ---------------- fallback (no workspace): slow but correct ----------------
__global__ __launch_bounds__(256) void fallback_k(const float* __restrict__ x,
                                                  const float* __restrict__ proto,
                                                  const float* __restrict__ lw,
                                                  float* __restrict__ out) {
    __shared__ float x2s[T_DIM];
    __shared__ float sims[P_DIM];
    int b = blockIdx.x, tid = threadIdx.x;
    for (int t = tid; t < T_DIM; t += 256) {
        float a = 0.f;
        for (int c = 0; c < C_DIM; ++c) { float v = x[((size_t)b * C_DIM + c) * T_DIM + t]; a = fmaf(v, v, a); }
        x2s[t] = a;
    }
    __syncthreads();
    for (int p = tid; p < P_DIM; p += 256) {
        float p2 = 0.f;
        for (int c = 0; c < C_DIM; ++c) { float v = proto[p * C_DIM + c]; p2 = fmaf(v, v, p2); }
        float mind = 1e30f;
        for (int t = 0; t < T_DIM; ++t) {
            float xp = 0.f;
            for (int c = 0; c < C_DIM; ++c)
                xp = fmaf(x[((size_t)b * C_DIM + c) * T_DIM + t], proto[p * C_DIM + c], xp);
            float d = fmaxf(x2s[t] - 2.f * xp + p2, 0.f);
            mind = fminf(mind, d);
        }
        sims[p] = logf((mind + 1.f) / (mind + EPSV));
    }
    __syncthreads();
    if (tid < NCLS) {
        float a = 0.f;
        for (int p = 0; p < P_DIM; ++p) a = fmaf(sims[p], lw[p * NCLS + tid], a);
        out[b * NCLS + tid] = a;
    }
}

extern "C" void kernel_launch(void* const* d_in, const int* in_sizes, int n_in,
                              void* d_out, int out_size, void* d_ws, size_t ws_size,
                              hipStream_t stream) {
    const float* x     = (const float*)d_in[0];
    const float* proto = (const float*)d_in[1];
    const float* lw    = (const float*)d_in[2];
    float* out = (float*)d_out;

    const size_t need = (size_t)3 * B_DIM * P_PAD * sizeof(float);   // 768 KB

    if (ws_size >= need) {
        float* wsmin = (float*)d_ws;
        fused_gemm_min<<<dim3(768), 256, 0, stream>>>(x, proto, wsmin);
        combine_logits<<<dim3(B_DIM), 256, 0, stream>>>(proto, lw, wsmin, out);
    } else {
        fallback_k<<<dim3(B_DIM), 256, 0, stream>>>(x, proto, lw, out);
    }
}